// Round 8
// baseline (894.025 us; speedup 1.0000x reference)
//
#include <hip/hip_runtime.h>
#include <math.h>

#define NI   50000
#define Tt   1000
#define KP   50176              // 50000 padded: 32 chunks x 1568 (=49*32)
#define MW   1568               // mask words per row (KP/32)

typedef __bf16 bf16x8 __attribute__((ext_vector_type(8)));
typedef float  f32x4  __attribute__((ext_vector_type(4)));

__device__ __forceinline__ unsigned short f2bf(float f) {
  unsigned u = __float_as_uint(f);
  u += 0x7FFFu + ((u >> 16) & 1u);   // RNE
  return (unsigned short)(u >> 16);
}
__device__ __forceinline__ float bf2f(unsigned short u) {
  return __uint_as_float(((unsigned)u) << 16);
}
__device__ __forceinline__ unsigned pack2(float a, float b) {
  return (unsigned)f2bf(a) | ((unsigned)f2bf(b) << 16);
}
__device__ __forceinline__ f32x4 mfma16(const unsigned short* a, const unsigned short* b, f32x4 c) {
  typedef unsigned short u16x8 __attribute__((ext_vector_type(8)));
  u16x8 av = *(const u16x8*)a;
  u16x8 bv = *(const u16x8*)b;
  return __builtin_amdgcn_mfma_f32_16x16x32_bf16(
      __builtin_bit_cast(bf16x8, av), __builtin_bit_cast(bf16x8, bv), c, 0, 0, 0);
}
__device__ __forceinline__ float gelu_f(float x) {
  return 0.5f * x * (1.f + erff(x * 0.70710678118654752f));
}

#define GLD16(gsrc, ldst) __builtin_amdgcn_global_load_lds( \
    (const __attribute__((address_space(1))) unsigned int*)(const void*)(gsrc), \
    (__attribute__((address_space(3))) unsigned int*)(void*)(ldst), 16, 0, 0)
#define GLD4(gsrc, ldst) __builtin_amdgcn_global_load_lds( \
    (const __attribute__((address_space(1))) unsigned int*)(const void*)(gsrc), \
    (__attribute__((address_space(3))) unsigned int*)(void*)(ldst), 4, 0, 0)

#define PIPE_FENCE() __builtin_amdgcn_sched_barrier(0)
#define RAW_BAR()    __builtin_amdgcn_s_barrier()

// ---------------------------------------------------------------------------
// prep_crit (thin-block, barrier-light):
//   [0, 6272)      bm: one thread = one mask word (8 indep float4 loads).
//   [6272, 19072)  cvt_w1: thin (row, chunk) blocks, 2048 cols each.
// ---------------------------------------------------------------------------
#define PC_BM 6272
#define PC_W1 19072

__global__ __launch_bounds__(256) void prep_crit(
    const float* __restrict__ x0, unsigned int* __restrict__ xmask,
    unsigned int* __restrict__ xmaskT,
    const float* __restrict__ enc_w1, unsigned short* __restrict__ w1b)
{
  __shared__ unsigned int T[32][8];
  const int id = blockIdx.x, tid = threadIdx.x;
  if (id < PC_BM) {
    const int rg = id / 196, wc = id % 196;
    const int r0 = rg * 32, w0 = wc * 8;
    const int rr = tid >> 3, wd = tid & 7;
    const int row = r0 + rr;
    const int gw = w0 + wd;              // global word index, < MW always
    const int cb = gw * 32;              // col base
    const float* rp = x0 + (size_t)row * NI + cb;
    unsigned wv = 0;
    if (cb + 32 <= NI) {
#pragma unroll
      for (int k = 0; k < 8; ++k) {
        float4 v = *(const float4*)(rp + k * 4);
        wv |= (v.x != 0.f ? 1u : 0u) << (k * 4) |
              (v.y != 0.f ? 2u : 0u) << (k * 4) |
              (v.z != 0.f ? 4u : 0u) << (k * 4) |
              (v.w != 0.f ? 8u : 0u) << (k * 4);
      }
    } else {
      for (int k = 0; k < 32; ++k)
        if (cb + k < NI && rp[k] != 0.f) wv |= 1u << k;
    }
    T[rr][wd] = wv;
    xmask[(size_t)row * MW + gw] = wv;   // row-major, straight from regs
    __syncthreads();
    // transpose writeout: 32 threads per word-column, 128 B contiguous
    int wq = tid >> 5, r2 = tid & 31;
    xmaskT[(size_t)(w0 + wq) * 1024 + r0 + r2] = T[r2][wq];
  } else {
    int q = id - PC_BM;
    int r = q / 25, ch = q % 25;
    int c = ch * 2048 + tid * 8;
    if (c >= KP) return;
    const float* s = enc_w1 + (size_t)r * NI;
    uint4 o;
    if (c + 8 <= NI) {
      float4 a = *(const float4*)(s + c), b = *(const float4*)(s + c + 4);
      o.x = pack2(a.x, a.y); o.y = pack2(a.z, a.w);
      o.z = pack2(b.x, b.y); o.w = pack2(b.z, b.w);
    } else {
      float v[8];
#pragma unroll
      for (int i = 0; i < 8; ++i) v[i] = (c + i < NI) ? s[c + i] : 0.f;
      o.x = pack2(v[0], v[1]); o.y = pack2(v[2], v[3]);
      o.z = pack2(v[4], v[5]); o.w = pack2(v[6], v[7]);
    }
    *(uint4*)(w1b + (size_t)r * KP + c) = o;
  }
}

// ---------------------------------------------------------------------------
// enc_fused: enc GEMM (blocks [0,1024)) + independent late prep fused in.
// ---------------------------------------------------------------------------
#define EF_ENC  1024
#define EF_W2N  2592
#define EF_MANY 3040
#define EF_COMP 3808
#define EF_TE   4832

__global__ __launch_bounds__(256) void enc_fused(
    const unsigned int* __restrict__ xmaskT,
    const unsigned short* __restrict__ Bw,
    float* __restrict__ P0, float* __restrict__ P1,
    const float* __restrict__ dec_w2, unsigned short* __restrict__ w2n,
    const float* s0a, const float* s1a, const float* s2a, const float* s3a,
    const float* s4a, const float* s5a, const float* s6a,
    unsigned short* d0a, unsigned short* d1a, unsigned short* d2a, unsigned short* d3a,
    unsigned short* d4a, unsigned short* d5a, unsigned short* d6a,
    const float* __restrict__ ca_wqkv, const float* __restrict__ ca_bqkv,
    const float* __restrict__ ip_w, const float* __restrict__ ip_b,
    const float* __restrict__ sa_wqkv, const float* __restrict__ sa_bqkv,
    const float* __restrict__ sa_wo, const float* __restrict__ sa_bo,
    unsigned short* __restrict__ Wkv, float* __restrict__ bkv,
    unsigned short* __restrict__ Wsa, float* __restrict__ bsa,
    const int* __restrict__ t,
    const float* __restrict__ te_w1, const float* __restrict__ te_b1,
    const float* __restrict__ te_w2, const float* __restrict__ te_b2,
    float* __restrict__ te, float* __restrict__ sab, float* __restrict__ s1ab)
{
  __shared__ __align__(16) unsigned short BsE[2][2][128 * 32];   // 32 KB
  __shared__ __align__(16) unsigned short lut[256][8];           // 4 KB
  __shared__ unsigned int mskb[2][2][128];                       // 2 KB
  __shared__ float sj[32];
  const int id = blockIdx.x, tid = threadIdx.x;

  if (id < EF_ENC) {
    const int g = (id & 7) + 8 * (id >> 6);
    const int m0 = ((id >> 3) & 7) * 128;
    const int n0 = (g & 3) * 128;
    const int kc = g >> 2;                 // 0..31
    const int kb = kc * 1568;
    const int kw0 = kc * 49;
    const int w = tid >> 6, l = tid & 63;
    const int wm = (w >> 1) * 64, wn = (w & 1) * 64;
    const int fr = l & 15, fo = (l >> 4) * 8;
    const int s0 = tid, s1 = tid + 256;
    const unsigned short* Br0 = Bw + (size_t)(n0 + (s0 >> 2)) * KP + kb + (s0 & 3) * 8;
    const unsigned short* Br1 = Bw + (size_t)(n0 + (s1 >> 2)) * KP + kb + (s1 & 3) * 8;
    f32x4 acc[4][4] = {};

    // LUT init: entry tid = 8 bf16 decoded from bits of tid
    {
      unsigned b = (unsigned)tid;
      uint4 q;
      q.x = (b & 1u   ? 0x3F80u : 0u) | (b & 2u   ? 0x3F800000u : 0u);
      q.y = (b & 4u   ? 0x3F80u : 0u) | (b & 8u   ? 0x3F800000u : 0u);
      q.z = (b & 16u  ? 0x3F80u : 0u) | (b & 32u  ? 0x3F800000u : 0u);
      q.w = (b & 64u  ? 0x3F80u : 0u) | (b & 128u ? 0x3F800000u : 0u);
      *(uint4*)&lut[tid][0] = q;
    }

#define STGF(IT, BUF) do {                                                  \
    GLD4(xmaskT + (size_t)(kw0 + (IT) * 2 + (w & 1)) * 1024                 \
                + m0 + (w >> 1) * 64 + l,                                   \
         &mskb[BUF][w & 1][(w >> 1) * 64]);                                 \
    GLD16(Br0 + (IT) * 64,      &BsE[BUF][0][s0 * 8]);                      \
    GLD16(Br1 + (IT) * 64,      &BsE[BUF][0][s1 * 8]);                      \
    GLD16(Br0 + (IT) * 64 + 32, &BsE[BUF][1][s0 * 8]);                      \
    GLD16(Br1 + (IT) * 64 + 32, &BsE[BUF][1][s1 * 8]); } while (0)

#define STGT(BUF) do {                                                      \
    GLD4(xmaskT + (size_t)(kw0 + 48) * 1024 + m0 + (w & 1) * 64 + l,        \
         &mskb[BUF][0][(w & 1) * 64]);                                      \
    GLD16(Br0 + 24 * 64, &BsE[BUF][0][s0 * 8]);                             \
    GLD16(Br1 + 24 * 64, &BsE[BUF][0][s1 * 8]); } while (0)

#define CMPH(BUF, KK) do {                                                  \
    const unsigned short *ap_[4], *bp_[4];                                  \
    _Pragma("unroll") for (int i_ = 0; i_ < 4; ++i_)                        \
      ap_[i_] = &lut[(mskb[BUF][KK][wm + 16 * i_ + fr] >> fo) & 0xFF][0];   \
    _Pragma("unroll") for (int j_ = 0; j_ < 4; ++j_)                        \
      bp_[j_] = &BsE[BUF][KK][(wn + 16 * j_ + fr) * 32 + fo];               \
    _Pragma("unroll") for (int i_ = 0; i_ < 4; ++i_)                        \
    _Pragma("unroll") for (int j_ = 0; j_ < 4; ++j_)                        \
      acc[i_][j_] = mfma16(ap_[i_], bp_[j_], acc[i_][j_]); } while (0)

    STGF(0, 0);
    STGF(1, 1);
    asm volatile("s_waitcnt vmcnt(5) lgkmcnt(0)" ::: "memory");
    PIPE_FENCE(); RAW_BAR(); PIPE_FENCE();
    for (int it = 0; it < 24; ++it) {
      CMPH(it & 1, 0);
      CMPH(it & 1, 1);
      PIPE_FENCE(); RAW_BAR(); PIPE_FENCE();
      if (it < 22) {
        STGF(it + 2, it & 1);
        asm volatile("s_waitcnt vmcnt(5)" ::: "memory");
      } else if (it == 22) {
        STGT(0);
        asm volatile("s_waitcnt vmcnt(3)" ::: "memory");
      } else {
        asm volatile("s_waitcnt vmcnt(0)" ::: "memory");
      }
      PIPE_FENCE(); RAW_BAR(); PIPE_FENCE();
    }
    CMPH(0, 0);                         // tail: k 1536..1567 in buf0 half0
#undef STGF
#undef STGT
#undef CMPH

    const int cr = (l >> 4) * 4, cc = l & 15;
    float* Cp = ((kc < 16) ? P0 : P1) + (size_t)(kc & 15) * 524288;
#pragma unroll
    for (int i = 0; i < 4; ++i)
#pragma unroll
      for (int j = 0; j < 4; ++j) {
        int n = n0 + wn + 16 * j + cc;
#pragma unroll
        for (int r = 0; r < 4; ++r) {
          int m = m0 + wm + 16 * i + cr + r;
          Cp[(size_t)m * 512 + n] = acc[i][j][r];
        }
      }
  } else if (id < EF_W2N) {
    // ---- cvt_w2n (grid-stride) ----
    size_t b2 = id - EF_ENC;
    for (size_t e = (b2 * 256 + tid) * 8; e < 25600000u; e += (size_t)1568 * 256 * 8) {
      float4 a = *(const float4*)(dec_w2 + e), b = *(const float4*)(dec_w2 + e + 4);
      uint4 o;
      o.x = pack2(a.x, a.y); o.y = pack2(a.z, a.w);
      o.z = pack2(b.x, b.y); o.w = pack2(b.z, b.w);
      *(uint4*)(w2n + e) = o;
    }
  } else if (id < EF_MANY) {
    // ---- cvt_many ----
    const float* srcs[7] = {s0a, s1a, s2a, s3a, s4a, s5a, s6a};
    unsigned short* dsts[7] = {d0a, d1a, d2a, d3a, d4a, d5a, d6a};
    const int ns[7] = {131072, 65536, 65536, 65536, 131072, 131072, 131072};
    int q = id - EF_W2N;
    int j = q >> 6;
    int i = ((q & 63) * 256 + tid) * 8;
    if (i >= ns[j]) return;
    float4 a = *(const float4*)(srcs[j] + i), b = *(const float4*)(srcs[j] + i + 4);
    uint4 o;
    o.x = pack2(a.x, a.y); o.y = pack2(a.z, a.w);
    o.z = pack2(b.x, b.y); o.w = pack2(b.z, b.w);
    *(uint4*)(dsts[j] + i) = o;
  } else if (id < EF_COMP) {
    // ---- compose_k ----
    int b = id - EF_MANY, k = tid;
    if (b < 512) {
      const float* wrow = ca_wqkv + (size_t)(256 + b) * 256;
      float s = 0.f;
      for (int c = 0; c < 256; ++c) s += wrow[c] * ip_w[c * 256 + k];
      Wkv[b * 256 + k] = f2bf(s);
      if (k == 0) {
        float sb = 0.f;
        for (int c = 0; c < 256; ++c) sb += wrow[c] * ip_b[c];
        bkv[b] = sb + ca_bqkv[256 + b];
      }
    } else {
      int i = b - 512;
      const float* worow = sa_wo + (size_t)i * 256;
      float s = 0.f;
      for (int c = 0; c < 256; ++c) s += worow[c] * sa_wqkv[(512 + c) * 256 + k];
      Wsa[i * 256 + k] = f2bf(s);
      if (k == 0) {
        float sb = 0.f;
        for (int c = 0; c < 256; ++c) sb += worow[c] * sa_bqkv[512 + c];
        bsa[i] = sb + sa_bo[i];
      }
    }
  } else {
    // ---- prep_te ----
    int b = id - EF_COMP, d = tid;
    int ti = t[b];
    float tn = (float)ti / (float)Tt;
    if (d < 32) {
      float a = tn * te_w1[d] + te_b1[d];
      sj[d] = a / (1.f + __expf(-a));
    }
    if (d == 0) {
      double tt = (double)(ti + 1) / (double)Tt;
      double c  = cos((tt + 0.008) / 1.008 * M_PI * 0.5);
      double c0 = cos((0.008) / 1.008 * M_PI * 0.5);
      double ab = (c * c) / (c0 * c0);
      sab[b]  = (float)sqrt(ab);
      s1ab[b] = (float)sqrt(1.0 - ab);
    }
    __syncthreads();
    float accv = te_b2[d];
#pragma unroll
    for (int j = 0; j < 32; ++j) accv += sj[j] * te_w2[d * 32 + j];
    te[(size_t)b * 256 + d] = accv;
  }
}

// ---------------------------------------------------------------------------
// gemm128: 128x128 tile, pure GLD16 staging, C bf16 = acc + bias (kv path)
// ---------------------------------------------------------------------------
__global__ __launch_bounds__(256) void gemm128(
    const unsigned short* __restrict__ A, int lda,
    const unsigned short* __restrict__ Bw, int ldb,
    const float* __restrict__ bias, void* __restrict__ Cv, int ldc, int K)
{
  __shared__ __align__(16) unsigned short As[128 * 32];
  __shared__ __align__(16) unsigned short Bs[128 * 32];
  const int tid = threadIdx.x;
  const int m0 = blockIdx.x * 128, n0 = blockIdx.y * 128;
  const int iters = K >> 5;
  const int w = tid >> 6, l = tid & 63;
  const int wm = (w >> 1) * 64, wn = (w & 1) * 64;
  const int fr = l & 15, fo = (l >> 4) * 8;
  const int s0 = tid, s1 = tid + 256;
  f32x4 acc[4][4] = {};
  for (int it = 0; it < iters; ++it) {
    int k0 = it * 32;
    __syncthreads();
    GLD16(A  + (size_t)(m0 + (s0 >> 2)) * lda + k0 + (s0 & 3) * 8, &As[s0 * 8]);
    GLD16(A  + (size_t)(m0 + (s1 >> 2)) * lda + k0 + (s1 & 3) * 8, &As[s1 * 8]);
    GLD16(Bw + (size_t)(n0 + (s0 >> 2)) * ldb + k0 + (s0 & 3) * 8, &Bs[s0 * 8]);
    GLD16(Bw + (size_t)(n0 + (s1 >> 2)) * ldb + k0 + (s1 & 3) * 8, &Bs[s1 * 8]);
    __syncthreads();
    const unsigned short *ap[4], *bp[4];
#pragma unroll
    for (int i = 0; i < 4; ++i) {
      ap[i] = &As[(wm + 16 * i + fr) * 32 + fo];
      bp[i] = &Bs[(wn + 16 * i + fr) * 32 + fo];
    }
#pragma unroll
    for (int i = 0; i < 4; ++i)
#pragma unroll
      for (int j = 0; j < 4; ++j)
        acc[i][j] = mfma16(ap[i], bp[j], acc[i][j]);
  }
  const int cr = (l >> 4) * 4, cc = l & 15;
  unsigned short* Cb = (unsigned short*)Cv;
#pragma unroll
  for (int j = 0; j < 4; ++j) {
    int n = n0 + wn + 16 * j + cc;
    float bv = bias[n];
#pragma unroll
    for (int i = 0; i < 4; ++i)
#pragma unroll
      for (int r = 0; r < 4; ++r) {
        int m = m0 + wm + 16 * i + cr + r;
        Cb[(size_t)m * ldc + n] = f2bf(acc[i][j][r] + bv);
      }
  }
}

// ---------------------------------------------------------------------------
// dec_gemm: decoder loss GEMM, 128x256 tile (per wave 64x128: 32 MFMA/iter —
// 2x barrier amortization vs 128x128). K=512, 16 iters, single-buffer m97
// staging. 1600 blocks: n = (id&7)+8*(id>>6) (<196 guard), m = (id>>3)&7;
// same-n group => same XCD, 256-wide B panel fetched once per XCD.
// Epilogue: softplus recon loss vs xmask bits, atomic per block.
// ---------------------------------------------------------------------------
__global__ __launch_bounds__(256) void dec_gemm(
    const unsigned short* __restrict__ A,      // Gb 1024x512
    const unsigned short* __restrict__ Bw,     // w2n 50000x512 (pad garbage ok)
    const float* __restrict__ bias,
    const unsigned int* __restrict__ xmask, float* __restrict__ loss, int Nvalid)
{
  __shared__ __align__(16) unsigned short As[128 * 32];   // 8 KB
  __shared__ __align__(16) unsigned short Bs[256 * 32];   // 16 KB
  __shared__ unsigned int msk[128][8];                    // 4 KB
  __shared__ float red[4];
  const int tid = threadIdx.x;
  const int id = blockIdx.x;
  const int n = (id & 7) + 8 * (id >> 6);
  if (n >= 196) return;
  const int m0 = ((id >> 3) & 7) * 128;
  const int n0 = n * 256;
  const int w = tid >> 6, l = tid & 63;
  const int wm = (w >> 1) * 64, wn = (w & 1) * 128;
  const int fr = l & 15, fo = (l >> 4) * 8;
  const int s0 = tid, s1 = tid + 256;                     // A granules
  const int b0 = tid, b1 = tid + 256, b2 = tid + 512, b3 = tid + 768;
  f32x4 acc[4][8] = {};
  for (int it = 0; it < 16; ++it) {
    int k0 = it * 32;
    __syncthreads();
    GLD16(A  + (size_t)(m0 + (s0 >> 2)) * 512 + k0 + (s0 & 3) * 8, &As[s0 * 8]);
    GLD16(A  + (size_t)(m0 + (s1 >> 2)) * 512 + k0 + (s1 & 3) * 8, &As[s1 * 8]);
    GLD16(Bw + (size_t)(n0 + (b0 >> 2)) * 512 + k0 + (b0 & 3) * 8, &Bs[b0 * 8]);
    GLD16(Bw + (size_t)(n0 + (b1 >> 2)) * 512 + k0 + (b1 & 3) * 8, &Bs[b1 * 8]);
    GLD16(Bw + (size_t)(n0 + (b2 >> 2)) * 512 + k0 + (b2 & 3) * 8, &Bs[b2 * 8]);
    GLD16(Bw + (size_t)(n0 + (b3 >> 2)) * 512 + k0 + (b3 & 3) * 8, &Bs[b3 * 8]);
    __syncthreads();
    const unsigned short *ap[4], *bp[8];
#pragma unroll
    for (int i = 0; i < 4; ++i)
      ap[i] = &As[(wm + 16 * i + fr) * 32 + fo];
#pragma unroll
    for (int j = 0; j < 8; ++j)
      bp[j] = &Bs[(wn + 16 * j + fr) * 32 + fo];
#pragma unroll
    for (int i = 0; i < 4; ++i)
#pragma unroll
      for (int j = 0; j < 8; ++j)
        acc[i][j] = mfma16(ap[i], bp[j], acc[i][j]);
  }
  // stage mask tile: 128 rows x 8 words (uint4 per thread-half)
  {
    int row = tid >> 1, p = tid & 1;
    *(uint4*)&msk[row][p * 4] =
        *(const uint4*)(xmask + (size_t)(m0 + row) * MW + (n0 >> 5) + p * 4);
  }
  __syncthreads();
  const int cr = (l >> 4) * 4, cc = l & 15;
  float ts = 0.f;
#pragma unroll
  for (int j = 0; j < 8; ++j) {
    int nl = wn + 16 * j + cc;
    int nn = n0 + nl;
    if (nn < Nvalid) {
      float bv = bias[nn];
#pragma unroll
      for (int i = 0; i < 4; ++i)
#pragma unroll
        for (int r = 0; r < 4; ++r) {
          int ml = wm + 16 * i + cr + r;
          float lg = acc[i][j][r] + bv;
          float sp = fmaxf(lg, 0.f) + __logf(1.f + __expf(-fabsf(lg)));
          unsigned word = msk[ml][nl >> 5];
          ts += sp - (((word >> (nl & 31)) & 1u) ? lg : 0.f);
        }
    }
  }
  for (int off = 32; off > 0; off >>= 1) ts += __shfl_xor(ts, off);
  if (l == 0) red[w] = ts;
  __syncthreads();
  if (tid == 0) atomicAdd(loss, red[0] + red[1] + red[2] + red[3]);
}

// ---------------------------------------------------------------------------
// gemm64<EPI>: 64x64 tile GLD16 bf16 GEMM for the mid-chain (single-buffer)
// ---------------------------------------------------------------------------
template<int EPI>
__global__ __launch_bounds__(256) void gemm64(
    const unsigned short* __restrict__ A, int lda,
    const unsigned short* __restrict__ Bw, int ldb,
    const float* __restrict__ bias, void* __restrict__ Cv, int ldc, int K,
    const void* __restrict__ R0, const void* __restrict__ R1, const void* __restrict__ R2,
    void* __restrict__ W0, void* __restrict__ W1, float* __restrict__ loss)
{
  __shared__ __align__(16) unsigned short As[64 * 32];
  __shared__ __align__(16) unsigned short Bs[64 * 32];
  __shared__ float red[4];
  const int tid = threadIdx.x;
  const int m0 = blockIdx.x * 64, n0 = blockIdx.y * 64;
  const int w = tid >> 6, l = tid & 63;
  const int wm = (w >> 1) * 32, wn = (w & 1) * 32;
  const int fr = l & 15, fo = (l >> 4) * 8;
  const int srow = tid >> 2, scol = (tid & 3) * 8;
  f32x4 acc[2][2] = {};
  for (int k0 = 0; k0 < K; k0 += 32) {
    __syncthreads();
    GLD16(A  + (size_t)(m0 + srow) * lda + k0 + scol, &As[tid * 8]);
    GLD16(Bw + (size_t)(n0 + srow) * ldb + k0 + scol, &Bs[tid * 8]);
    __syncthreads();
    const unsigned short* ap0 = &As[(wm +      fr) * 32 + fo];
    const unsigned short* ap1 = &As[(wm + 16 + fr) * 32 + fo];
    const unsigned short* bp0 = &Bs[(wn +      fr) * 32 + fo];
    const unsigned short* bp1 = &Bs[(wn + 16 + fr) * 32 + fo];
    acc[0][0] = mfma16(ap0, bp0, acc[0][0]);
    acc[0][1] = mfma16(ap0, bp1, acc[0][1]);
    acc[1][0] = mfma16(ap1, bp0, acc[1][0]);
    acc[1][1] = mfma16(ap1, bp1, acc[1][1]);
  }
  const int cr = (l >> 4) * 4, cc = l & 15;
  float ts = 0.f;
#pragma unroll
  for (int i = 0; i < 2; ++i)
#pragma unroll
    for (int j = 0; j < 2; ++j) {
      int n = n0 + wn + 16 * j + cc;
      float bv = bias[n];
#pragma unroll
      for (int r = 0; r < 4; ++r) {
        int m = m0 + wm + 16 * i + cr + r;
        float v = acc[i][j][r] + bv;
        size_t idx = (size_t)m * ldc + n;
        if (EPI == 0) ((float*)Cv)[idx] = v;
        if (EPI == 1) ((unsigned short*)Cv)[idx] = f2bf(v);
        if (EPI == 2) ((unsigned short*)Cv)[idx] = f2bf(gelu_f(v));
        if (EPI == 3) {
          ((float*)Cv)[idx] = v;
          ((unsigned short*)W0)[idx] = f2bf(v);
          float zt = ((const float*)R1)[m] * v +
                     ((const float*)R2)[m] * ((const float*)R0)[idx];
          ((unsigned short*)W1)[idx] = f2bf(zt);
        }
        if (EPI == 4) {
          v += ((const float*)R0)[idx];
          ((unsigned short*)Cv)[idx] = f2bf(v);
        }
        if (EPI == 5) {
          v += bf2f(((const unsigned short*)R0)[idx]);
          float d = v - ((const float*)R1)[idx];
          ts += d * d;
        }
      }
    }
  if (EPI == 5) {
    for (int off = 32; off > 0; off >>= 1) ts += __shfl_xor(ts, off);
    if (l == 0) red[w] = ts;
    __syncthreads();
    if (tid == 0) atomicAdd(loss, red[0] + red[1] + red[2] + red[3]);
  }
}

// H1b = gelu(sum_k P0[k]+P1[k] + enc_b1) -> bf16, 1024x512; 32-slice reduce
__global__ __launch_bounds__(256) void h1_epi(const float* __restrict__ P0,
                                              const float* __restrict__ P1,
                                              const float* __restrict__ b,
                                              unsigned short* __restrict__ H) {
  int i = blockIdx.x * 256 + threadIdx.x;
  float s = b[i & 511];
#pragma unroll
  for (int k = 0; k < 16; ++k) s += P0[(size_t)k * 524288 + i];
#pragma unroll
  for (int k = 0; k < 16; ++k) s += P1[(size_t)k * 524288 + i];
  H[i] = f2bf(gelu_f(s));
}

// gather neighbors -> bf16 (one block per batch row, 20 neighbors)
__global__ __launch_bounds__(256) void gather_nb(
    const int* __restrict__ uid, const int* __restrict__ nidx,
    const float* __restrict__ emb, unsigned short* __restrict__ nb)
{
  int b = blockIdx.x, d = threadIdx.x;
  const int* np = nidx + uid[b] * 20;
#pragma unroll
  for (int j = 0; j < 20; ++j) {
    int idx = np[j];
    nb[((size_t)b * 20 + j) * 256 + d] = f2bf(emb[(size_t)idx * 256 + d]);
  }
}

// cross-attention core: 20 keys, one wave per (b, head); kvh bf16
__global__ __launch_bounds__(256) void attn_k(
    const float* __restrict__ qh, const unsigned short* __restrict__ kvh,
    unsigned short* __restrict__ o)
{
  int b = blockIdx.x, tid = threadIdx.x;
  int h = tid >> 6, d = tid & 63;
  float qv = qh[(size_t)b * 256 + h * 64 + d];
  const unsigned short* kbase = kvh + (size_t)b * 20 * 512 + h * 64 + d;
  const unsigned short* vbase = kbase + 256;
  float s[20];
#pragma unroll
  for (int k = 0; k < 20; ++k) {
    float p = qv * bf2f(kbase[k * 512]);
    for (int off = 32; off > 0; off >>= 1) p += __shfl_xor(p, off);
    s[k] = p * 0.125f;
  }
  float mx = s[0];
#pragma unroll
  for (int k = 1; k < 20; ++k) mx = fmaxf(mx, s[k]);
  float sum = 0.f;
#pragma unroll
  for (int k = 0; k < 20; ++k) { s[k] = __expf(s[k] - mx); sum += s[k]; }
  float inv = 1.f / sum;
  float ov = 0.f;
#pragma unroll
  for (int k = 0; k < 20; ++k) ov += s[k] * bf2f(vbase[k * 512]);
  o[(size_t)b * 256 + h * 64 + d] = f2bf(ov * inv);
}

// LayerNorm(X + Y), bf16 in/out
__global__ __launch_bounds__(256) void ln_k(
    const unsigned short* __restrict__ X, const unsigned short* __restrict__ Y,
    const float* __restrict__ g, const float* __restrict__ bb,
    unsigned short* __restrict__ out)
{
  __shared__ float rs[4], rs2[4];
  int b = blockIdx.x, d = threadIdx.x;
  size_t i = (size_t)b * 256 + d;
  float v = bf2f(X[i]) + bf2f(Y[i]);
  float s = v, s2 = v * v;
  for (int off = 32; off > 0; off >>= 1) { s += __shfl_xor(s, off); s2 += __shfl_xor(s2, off); }
  int w = d >> 6, l = d & 63;
  if (l == 0) { rs[w] = s; rs2[w] = s2; }
  __syncthreads();
  s  = rs[0] + rs[1] + rs[2] + rs[3];
  s2 = rs2[0] + rs2[1] + rs2[2] + rs2[3];
  float mean = s * (1.f / 256.f);
  float var  = s2 * (1.f / 256.f) - mean * mean;
  out[i] = f2bf((v - mean) * rsqrtf(var + 1e-5f) * g[d] + bb[d]);
}

__global__ void final_k(const float* __restrict__ scal, float* __restrict__ out) {
  out[0] = scal[0] * (1.f / (1024.f * 256.f)) + 0.1f * scal[1] * (1.f / (1024.f * 50000.f));
}

// ---------------------------------------------------------------------------
extern "C" void kernel_launch(void* const* d_in, const int* in_sizes, int n_in,
                              void* d_out, int out_size, void* d_ws, size_t ws_size,
                              hipStream_t stream) {
  const float* x0      = (const float*)d_in[0];
  const int*   uid     = (const int*)  d_in[1];
  const int*   t       = (const int*)  d_in[2];
  const float* noise   = (const float*)d_in[3];
  const int*   nidx    = (const int*)  d_in[4];
  const float* item_emb= (const float*)d_in[5];
  const float* enc_w1  = (const float*)d_in[6];
  const float* enc_b1  = (const float*)d_in[7];
  const float* enc_w2  = (const float*)d_in[8];
  const float* enc_b2  = (const float*)d_in[9];
  const float* dec_w1  = (const float*)d_in[10];
  const float* dec_b1  = (const float*)d_in[11];
  const float* dec_w2  = (const float*)d_in[12];
  const float* dec_b2  = (const float*)d_in[13];
  const float* up_w    = (const float*)d_in[14];
  const float* up_b    = (const float*)d_in[15];
  const float* ip_w    = (const float*)d_in[16];
  const float* ip_b    = (const float*)d_in[17];
  const float* te_w1   = (const float*)d_in[18];
  const float* te_b1   = (const float*)d_in[19];
  const float* te_w2   = (const float*)d_in[20];
  const float* te_b2   = (const float*)d_in[21];
  const float* ca_wqkv = (const float*)d_in[22];
  const float* ca_bqkv = (const float*)d_in[23];
  const float* ca_wo   = (const float*)d_in[24];
  const float* ca_bo   = (const float*)d_in[25];
  const float* sa_wqkv = (const float*)d_in[26];
  const float* sa_bqkv = (const float*)d_in[27];
  const float* sa_wo   = (const float*)d_in[28];
  const float* sa_bo   = (const float*)d_in[29];
  const float* n1_g    = (const float*)d_in[30];
  const float* n1_b    = (const float*)d_in[31];
  const float* n2_g    = (const float*)d_in[32];
  const float* n2_b    = (const float*)d_in[33];
  const float* ff_w1   = (const float*)d_in[34];
  const float* ff_b1   = (const float*)d_in[35];
  const float* ff_w2   = (const float*)d_in[36];
  const float* ff_b2   = (const float*)d_in[37];
  (void)in_sizes; (void)n_in; (void)out_size; (void)ws_size;

  float* ws   = (float*)d_ws;
  float* scal = ws;                    // 4 (diff, recon)
  float* sab  = ws + 4;                // 1024
  float* s1ab = sab + 1024;
  float* te   = s1ab + 1024;           // 1024*256
  float* qhf  = te + 262144;           // 1024*256
  float* z0f  = qhf + 262144;          // 1024*256
  float* bkv  = z0f + 262144;          // 512
  float* bsa  = bkv + 512;             // 256
  unsigned int* xmask = (unsigned int*)(bsa + 256);           // 1024*MW
  // P-pool bank0: slices 0-15 (33,554,432 B) aliases [nbb|kvhb|f1b|Gb]
  unsigned short* sh  = (unsigned short*)(xmask + 1024 * MW);
  float*          OUTp = (float*)sh;                          // 8,388,608 f32
  unsigned short* nbb  = sh;                                  // 20480*256
  unsigned short* kvhb = nbb + 5242880;                       // 20480*512
  unsigned short* f1b  = kvhb + 10485760;                     // 1024*512
  unsigned short* Gb   = f1b + 524288;                        // 1024*512
  unsigned short* x0b  = Gb + 524288;                         // dead region: holds w2n + xmaskT
  unsigned short* w2n  = x0b;                                 // 25.6M shorts
  unsigned int*   xmaskT = (unsigned int*)(x0b + 26214400);   // MW*1024 words (6.4 MB)
  unsigned short* w1b  = x0b + (size_t)1024 * KP;             // 512*KP
  unsigned short* H1b  = w1b + (size_t)512 * KP;              // 1024*512
  unsigned short* z0b  = H1b + 524288;
  unsigned short* ztb  = z0b + 262144;
  unsigned short* qpb  = ztb + 262144;
  unsigned short* ob   = qpb + 262144;
  unsigned short* cab  = ob  + 262144;
  unsigned short* hb   = cab + 262144;
  unsigned short* saob = hb  + 262144;
  unsigned short* h2b  = saob+ 262144;
  unsigned short* enc_w2b = h2b + 262144;                     // 131072
  unsigned short* up_wb   = enc_w2b + 131072;
  unsigned short* ca_wqb  = up_wb + 65536;
  unsigned short* ca_wob  = ca_wqb + 65536;
  unsigned short* ff_w1b  = ca_wob + 65536;
  unsigned short* ff_w2b  = ff_w1b + 131072;
  unsigned short* dec_w1b = ff_w2b + 131072;
  unsigned short* Wkv     = dec_w1b + 131072;
  unsigned short* Wsab    = Wkv + 131072;
  // P-pool bank1: slices 16-31
  float*          OUTp2   = (float*)(Wsab + 131072);          // 8,388,608 f32

  hipMemsetAsync(scal, 0, 4 * sizeof(float), stream);

  // critical prep: bits (both layouts) + w1 bf16 — thin blocks, barrier-light
  prep_crit<<<PC_W1, 256, 0, stream>>>(x0, xmask, xmaskT, enc_w1, w1b);

  // enc GEMM (BK=64, transposed-mask GLD4) + all independent late prep fused
  enc_fused<<<EF_TE, 256, 0, stream>>>(
      xmaskT, w1b, OUTp, OUTp2,
      dec_w2, w2n,
      enc_w2, up_w, ca_wqkv, ca_wo, ff_w1, ff_w2, dec_w1,
      enc_w2b, up_wb, ca_wqb, ca_wob, ff_w1b, ff_w2b, dec_w1b,
      ca_wqkv, ca_bqkv, ip_w, ip_b, sa_wqkv, sa_bqkv, sa_wo, sa_bo,
      Wkv, bkv, Wsab, bsa,
      t, te_w1, te_b1, te_w2, te_b2, te, sab, s1ab);
  h1_epi<<<2048, 256, 0, stream>>>(OUTp, OUTp2, enc_b1, H1b);  // OUTp dead after

  // kv path (P-pool bank0 live again: OUTp dead)
  gather_nb<<<1024, 256, 0, stream>>>(uid, nidx, item_emb, nbb);
  gemm128<<<dim3(160, 4), 256, 0, stream>>>(
      nbb, 256, Wkv, 256, bkv, kvhb, 512, 256);

  // z0 GEMM + fused z_t
  gemm64<3><<<dim3(16, 4), 256, 0, stream>>>(
      H1b, 512, enc_w2b, 512, enc_b2, z0f, 256, 512, noise, sab, s1ab, z0b, ztb, nullptr);

  // q path
  gemm64<4><<<dim3(16, 4), 256, 0, stream>>>(
      ztb, 256, up_wb, 256, up_b, qpb, 256, 256, te, nullptr, nullptr, nullptr, nullptr, nullptr);
  gemm64<0><<<dim3(16, 4), 256, 0, stream>>>(
      qpb, 256, ca_wqb, 256, ca_bqkv, qhf, 256, 256,
      nullptr, nullptr, nullptr, nullptr, nullptr, nullptr);

  // attention + out-proj + LN1
  attn_k<<<1024, 256, 0, stream>>>(qhf, kvhb, ob);
  gemm64<1><<<dim3(16, 4), 256, 0, stream>>>(
      ob, 256, ca_wob, 256, ca_bo, cab, 256, 256,
      nullptr, nullptr, nullptr, nullptr, nullptr, nullptr);
  ln_k<<<1024, 256, 0, stream>>>(qpb, cab, n1_g, n1_b, hb);

  // self-attn (seq=1, composed) + LN2
  gemm64<1><<<dim3(16, 4), 256, 0, stream>>>(
      hb, 256, Wsab, 256, bsa, saob, 256, 256,
      nullptr, nullptr, nullptr, nullptr, nullptr, nullptr);
  ln_k<<<1024, 256, 0, stream>>>(hb, saob, n2_g, n2_b, h2b);

  // FF with fused residual + diffusion loss
  gemm64<2><<<dim3(16, 8), 256, 0, stream>>>(
      h2b, 256, ff_w1b, 256, ff_b1, f1b, 512, 256,
      nullptr, nullptr, nullptr, nullptr, nullptr, nullptr);
  gemm64<5><<<dim3(16, 4), 256, 0, stream>>>(
      f1b, 512, ff_w2b, 512, ff_b2, nullptr, 256, 512,
      h2b, z0f, nullptr, nullptr, nullptr, &scal[0]);

  // decoder: G = gelu(z0@dec_w1^T+b) bf16, then 128x256-tile GEMM + loss
  gemm64<2><<<dim3(16, 8), 256, 0, stream>>>(
      z0b, 256, dec_w1b, 256, dec_b1, Gb, 512, 256,
      nullptr, nullptr, nullptr, nullptr, nullptr, nullptr);
  dec_gemm<<<1600, 256, 0, stream>>>(
      Gb, w2n, dec_b2, xmask, &scal[1], NI);

  final_k<<<1, 1, 0, stream>>>(scal, (float*)d_out);
}

// Round 9
// 794.285 us; speedup vs baseline: 1.1256x; 1.1256x over previous
//
#include <hip/hip_runtime.h>
#include <math.h>

#define NI   50000
#define Tt   1000
#define KP   50176              // 50000 padded: 32 chunks x 1568 (=49*32)
#define MW   1568               // mask words per row (KP/32)

typedef __bf16 bf16x8 __attribute__((ext_vector_type(8)));
typedef float  f32x4  __attribute__((ext_vector_type(4)));

__device__ __forceinline__ unsigned short f2bf(float f) {
  unsigned u = __float_as_uint(f);
  u += 0x7FFFu + ((u >> 16) & 1u);   // RNE
  return (unsigned short)(u >> 16);
}
__device__ __forceinline__ float bf2f(unsigned short u) {
  return __uint_as_float(((unsigned)u) << 16);
}
__device__ __forceinline__ unsigned pack2(float a, float b) {
  return (unsigned)f2bf(a) | ((unsigned)f2bf(b) << 16);
}
__device__ __forceinline__ f32x4 mfma16(const unsigned short* a, const unsigned short* b, f32x4 c) {
  typedef unsigned short u16x8 __attribute__((ext_vector_type(8)));
  u16x8 av = *(const u16x8*)a;
  u16x8 bv = *(const u16x8*)b;
  return __builtin_amdgcn_mfma_f32_16x16x32_bf16(
      __builtin_bit_cast(bf16x8, av), __builtin_bit_cast(bf16x8, bv), c, 0, 0, 0);
}
__device__ __forceinline__ float gelu_f(float x) {
  return 0.5f * x * (1.f + erff(x * 0.70710678118654752f));
}

#define GLD16(gsrc, ldst) __builtin_amdgcn_global_load_lds( \
    (const __attribute__((address_space(1))) unsigned int*)(const void*)(gsrc), \
    (__attribute__((address_space(3))) unsigned int*)(void*)(ldst), 16, 0, 0)
#define GLD4(gsrc, ldst) __builtin_amdgcn_global_load_lds( \
    (const __attribute__((address_space(1))) unsigned int*)(const void*)(gsrc), \
    (__attribute__((address_space(3))) unsigned int*)(void*)(ldst), 4, 0, 0)

#define PIPE_FENCE() __builtin_amdgcn_sched_barrier(0)
#define RAW_BAR()    __builtin_amdgcn_s_barrier()

// ---------------------------------------------------------------------------
// prep_crit (thin-block, barrier-light):
//   [0, 6272)      bm: one thread = one mask word (8 indep float4 loads).
//   [6272, 19072)  cvt_w1: thin (row, chunk) blocks, 2048 cols each.
// ---------------------------------------------------------------------------
#define PC_BM 6272
#define PC_W1 19072

__global__ __launch_bounds__(256) void prep_crit(
    const float* __restrict__ x0, unsigned int* __restrict__ xmask,
    unsigned int* __restrict__ xmaskT,
    const float* __restrict__ enc_w1, unsigned short* __restrict__ w1b)
{
  __shared__ unsigned int T[32][8];
  const int id = blockIdx.x, tid = threadIdx.x;
  if (id < PC_BM) {
    const int rg = id / 196, wc = id % 196;
    const int r0 = rg * 32, w0 = wc * 8;
    const int rr = tid >> 3, wd = tid & 7;
    const int row = r0 + rr;
    const int gw = w0 + wd;              // global word index, < MW always
    const int cb = gw * 32;              // col base
    const float* rp = x0 + (size_t)row * NI + cb;
    unsigned wv = 0;
    if (cb + 32 <= NI) {
#pragma unroll
      for (int k = 0; k < 8; ++k) {
        float4 v = *(const float4*)(rp + k * 4);
        wv |= (v.x != 0.f ? 1u : 0u) << (k * 4) |
              (v.y != 0.f ? 2u : 0u) << (k * 4) |
              (v.z != 0.f ? 4u : 0u) << (k * 4) |
              (v.w != 0.f ? 8u : 0u) << (k * 4);
      }
    } else {
      for (int k = 0; k < 32; ++k)
        if (cb + k < NI && rp[k] != 0.f) wv |= 1u << k;
    }
    T[rr][wd] = wv;
    xmask[(size_t)row * MW + gw] = wv;   // row-major, straight from regs
    __syncthreads();
    // transpose writeout: 32 threads per word-column, 128 B contiguous
    int wq = tid >> 5, r2 = tid & 31;
    xmaskT[(size_t)(w0 + wq) * 1024 + r0 + r2] = T[r2][wq];
  } else {
    int q = id - PC_BM;
    int r = q / 25, ch = q % 25;
    int c = ch * 2048 + tid * 8;
    if (c >= KP) return;
    const float* s = enc_w1 + (size_t)r * NI;
    uint4 o;
    if (c + 8 <= NI) {
      float4 a = *(const float4*)(s + c), b = *(const float4*)(s + c + 4);
      o.x = pack2(a.x, a.y); o.y = pack2(a.z, a.w);
      o.z = pack2(b.x, b.y); o.w = pack2(b.z, b.w);
    } else {
      float v[8];
#pragma unroll
      for (int i = 0; i < 8; ++i) v[i] = (c + i < NI) ? s[c + i] : 0.f;
      o.x = pack2(v[0], v[1]); o.y = pack2(v[2], v[3]);
      o.z = pack2(v[4], v[5]); o.w = pack2(v[6], v[7]);
    }
    *(uint4*)(w1b + (size_t)r * KP + c) = o;
  }
}

// ---------------------------------------------------------------------------
// enc_fused: enc GEMM (blocks [0,1024)) + independent late prep fused in.
// ---------------------------------------------------------------------------
#define EF_ENC  1024
#define EF_W2N  2592
#define EF_MANY 3040
#define EF_COMP 3808
#define EF_TE   4832

__global__ __launch_bounds__(256) void enc_fused(
    const unsigned int* __restrict__ xmaskT,
    const unsigned short* __restrict__ Bw,
    float* __restrict__ P0, float* __restrict__ P1,
    const float* __restrict__ dec_w2, unsigned short* __restrict__ w2n,
    const float* s0a, const float* s1a, const float* s2a, const float* s3a,
    const float* s4a, const float* s5a, const float* s6a,
    unsigned short* d0a, unsigned short* d1a, unsigned short* d2a, unsigned short* d3a,
    unsigned short* d4a, unsigned short* d5a, unsigned short* d6a,
    const float* __restrict__ ca_wqkv, const float* __restrict__ ca_bqkv,
    const float* __restrict__ ip_w, const float* __restrict__ ip_b,
    const float* __restrict__ sa_wqkv, const float* __restrict__ sa_bqkv,
    const float* __restrict__ sa_wo, const float* __restrict__ sa_bo,
    unsigned short* __restrict__ Wkv, float* __restrict__ bkv,
    unsigned short* __restrict__ Wsa, float* __restrict__ bsa,
    const int* __restrict__ t,
    const float* __restrict__ te_w1, const float* __restrict__ te_b1,
    const float* __restrict__ te_w2, const float* __restrict__ te_b2,
    float* __restrict__ te, float* __restrict__ sab, float* __restrict__ s1ab)
{
  __shared__ __align__(16) unsigned short BsE[2][2][128 * 32];   // 32 KB
  __shared__ __align__(16) unsigned short lut[256][8];           // 4 KB
  __shared__ unsigned int mskb[2][2][128];                       // 2 KB
  __shared__ float sj[32];
  const int id = blockIdx.x, tid = threadIdx.x;

  if (id < EF_ENC) {
    const int g = (id & 7) + 8 * (id >> 6);
    const int m0 = ((id >> 3) & 7) * 128;
    const int n0 = (g & 3) * 128;
    const int kc = g >> 2;                 // 0..31
    const int kb = kc * 1568;
    const int kw0 = kc * 49;
    const int w = tid >> 6, l = tid & 63;
    const int wm = (w >> 1) * 64, wn = (w & 1) * 64;
    const int fr = l & 15, fo = (l >> 4) * 8;
    const int s0 = tid, s1 = tid + 256;
    const unsigned short* Br0 = Bw + (size_t)(n0 + (s0 >> 2)) * KP + kb + (s0 & 3) * 8;
    const unsigned short* Br1 = Bw + (size_t)(n0 + (s1 >> 2)) * KP + kb + (s1 & 3) * 8;
    f32x4 acc[4][4] = {};

    // LUT init: entry tid = 8 bf16 decoded from bits of tid
    {
      unsigned b = (unsigned)tid;
      uint4 q;
      q.x = (b & 1u   ? 0x3F80u : 0u) | (b & 2u   ? 0x3F800000u : 0u);
      q.y = (b & 4u   ? 0x3F80u : 0u) | (b & 8u   ? 0x3F800000u : 0u);
      q.z = (b & 16u  ? 0x3F80u : 0u) | (b & 32u  ? 0x3F800000u : 0u);
      q.w = (b & 64u  ? 0x3F80u : 0u) | (b & 128u ? 0x3F800000u : 0u);
      *(uint4*)&lut[tid][0] = q;
    }

#define STGF(IT, BUF) do {                                                  \
    GLD4(xmaskT + (size_t)(kw0 + (IT) * 2 + (w & 1)) * 1024                 \
                + m0 + (w >> 1) * 64 + l,                                   \
         &mskb[BUF][w & 1][(w >> 1) * 64]);                                 \
    GLD16(Br0 + (IT) * 64,      &BsE[BUF][0][s0 * 8]);                      \
    GLD16(Br1 + (IT) * 64,      &BsE[BUF][0][s1 * 8]);                      \
    GLD16(Br0 + (IT) * 64 + 32, &BsE[BUF][1][s0 * 8]);                      \
    GLD16(Br1 + (IT) * 64 + 32, &BsE[BUF][1][s1 * 8]); } while (0)

#define STGT(BUF) do {                                                      \
    GLD4(xmaskT + (size_t)(kw0 + 48) * 1024 + m0 + (w & 1) * 64 + l,        \
         &mskb[BUF][0][(w & 1) * 64]);                                      \
    GLD16(Br0 + 24 * 64, &BsE[BUF][0][s0 * 8]);                             \
    GLD16(Br1 + 24 * 64, &BsE[BUF][0][s1 * 8]); } while (0)

#define CMPH(BUF, KK) do {                                                  \
    const unsigned short *ap_[4], *bp_[4];                                  \
    _Pragma("unroll") for (int i_ = 0; i_ < 4; ++i_)                        \
      ap_[i_] = &lut[(mskb[BUF][KK][wm + 16 * i_ + fr] >> fo) & 0xFF][0];   \
    _Pragma("unroll") for (int j_ = 0; j_ < 4; ++j_)                        \
      bp_[j_] = &BsE[BUF][KK][(wn + 16 * j_ + fr) * 32 + fo];               \
    _Pragma("unroll") for (int i_ = 0; i_ < 4; ++i_)                        \
    _Pragma("unroll") for (int j_ = 0; j_ < 4; ++j_)                        \
      acc[i_][j_] = mfma16(ap_[i_], bp_[j_], acc[i_][j_]); } while (0)

    STGF(0, 0);
    STGF(1, 1);
    asm volatile("s_waitcnt vmcnt(5) lgkmcnt(0)" ::: "memory");
    PIPE_FENCE(); RAW_BAR(); PIPE_FENCE();
    for (int it = 0; it < 24; ++it) {
      CMPH(it & 1, 0);
      CMPH(it & 1, 1);
      PIPE_FENCE(); RAW_BAR(); PIPE_FENCE();
      if (it < 22) {
        STGF(it + 2, it & 1);
        asm volatile("s_waitcnt vmcnt(5)" ::: "memory");
      } else if (it == 22) {
        STGT(0);
        asm volatile("s_waitcnt vmcnt(3)" ::: "memory");
      } else {
        asm volatile("s_waitcnt vmcnt(0)" ::: "memory");
      }
      PIPE_FENCE(); RAW_BAR(); PIPE_FENCE();
    }
    CMPH(0, 0);                         // tail: k 1536..1567 in buf0 half0
#undef STGF
#undef STGT
#undef CMPH

    const int cr = (l >> 4) * 4, cc = l & 15;
    float* Cp = ((kc < 16) ? P0 : P1) + (size_t)(kc & 15) * 524288;
#pragma unroll
    for (int i = 0; i < 4; ++i)
#pragma unroll
      for (int j = 0; j < 4; ++j) {
        int n = n0 + wn + 16 * j + cc;
#pragma unroll
        for (int r = 0; r < 4; ++r) {
          int m = m0 + wm + 16 * i + cr + r;
          Cp[(size_t)m * 512 + n] = acc[i][j][r];
        }
      }
  } else if (id < EF_W2N) {
    // ---- cvt_w2n (grid-stride) ----
    size_t b2 = id - EF_ENC;
    for (size_t e = (b2 * 256 + tid) * 8; e < 25600000u; e += (size_t)1568 * 256 * 8) {
      float4 a = *(const float4*)(dec_w2 + e), b = *(const float4*)(dec_w2 + e + 4);
      uint4 o;
      o.x = pack2(a.x, a.y); o.y = pack2(a.z, a.w);
      o.z = pack2(b.x, b.y); o.w = pack2(b.z, b.w);
      *(uint4*)(w2n + e) = o;
    }
  } else if (id < EF_MANY) {
    // ---- cvt_many ----
    const float* srcs[7] = {s0a, s1a, s2a, s3a, s4a, s5a, s6a};
    unsigned short* dsts[7] = {d0a, d1a, d2a, d3a, d4a, d5a, d6a};
    const int ns[7] = {131072, 65536, 65536, 65536, 131072, 131072, 131072};
    int q = id - EF_W2N;
    int j = q >> 6;
    int i = ((q & 63) * 256 + tid) * 8;
    if (i >= ns[j]) return;
    float4 a = *(const float4*)(srcs[j] + i), b = *(const float4*)(srcs[j] + i + 4);
    uint4 o;
    o.x = pack2(a.x, a.y); o.y = pack2(a.z, a.w);
    o.z = pack2(b.x, b.y); o.w = pack2(b.z, b.w);
    *(uint4*)(dsts[j] + i) = o;
  } else if (id < EF_COMP) {
    // ---- compose_k ----
    int b = id - EF_MANY, k = tid;
    if (b < 512) {
      const float* wrow = ca_wqkv + (size_t)(256 + b) * 256;
      float s = 0.f;
      for (int c = 0; c < 256; ++c) s += wrow[c] * ip_w[c * 256 + k];
      Wkv[b * 256 + k] = f2bf(s);
      if (k == 0) {
        float sb = 0.f;
        for (int c = 0; c < 256; ++c) sb += wrow[c] * ip_b[c];
        bkv[b] = sb + ca_bqkv[256 + b];
      }
    } else {
      int i = b - 512;
      const float* worow = sa_wo + (size_t)i * 256;
      float s = 0.f;
      for (int c = 0; c < 256; ++c) s += worow[c] * sa_wqkv[(512 + c) * 256 + k];
      Wsa[i * 256 + k] = f2bf(s);
      if (k == 0) {
        float sb = 0.f;
        for (int c = 0; c < 256; ++c) sb += worow[c] * sa_bqkv[512 + c];
        bsa[i] = sb + sa_bo[i];
      }
    }
  } else {
    // ---- prep_te ----
    int b = id - EF_COMP, d = tid;
    int ti = t[b];
    float tn = (float)ti / (float)Tt;
    if (d < 32) {
      float a = tn * te_w1[d] + te_b1[d];
      sj[d] = a / (1.f + __expf(-a));
    }
    if (d == 0) {
      double tt = (double)(ti + 1) / (double)Tt;
      double c  = cos((tt + 0.008) / 1.008 * M_PI * 0.5);
      double c0 = cos((0.008) / 1.008 * M_PI * 0.5);
      double ab = (c * c) / (c0 * c0);
      sab[b]  = (float)sqrt(ab);
      s1ab[b] = (float)sqrt(1.0 - ab);
    }
    __syncthreads();
    float accv = te_b2[d];
#pragma unroll
    for (int j = 0; j < 32; ++j) accv += sj[j] * te_w2[d * 32 + j];
    te[(size_t)b * 256 + d] = accv;
  }
}

// ---------------------------------------------------------------------------
// gemm128: 128x128 tile, pure GLD16 staging, C bf16 = acc + bias (kv path)
// ---------------------------------------------------------------------------
__global__ __launch_bounds__(256) void gemm128(
    const unsigned short* __restrict__ A, int lda,
    const unsigned short* __restrict__ Bw, int ldb,
    const float* __restrict__ bias, void* __restrict__ Cv, int ldc, int K)
{
  __shared__ __align__(16) unsigned short As[128 * 32];
  __shared__ __align__(16) unsigned short Bs[128 * 32];
  const int tid = threadIdx.x;
  const int m0 = blockIdx.x * 128, n0 = blockIdx.y * 128;
  const int iters = K >> 5;
  const int w = tid >> 6, l = tid & 63;
  const int wm = (w >> 1) * 64, wn = (w & 1) * 64;
  const int fr = l & 15, fo = (l >> 4) * 8;
  const int s0 = tid, s1 = tid + 256;
  f32x4 acc[4][4] = {};
  for (int it = 0; it < iters; ++it) {
    int k0 = it * 32;
    __syncthreads();
    GLD16(A  + (size_t)(m0 + (s0 >> 2)) * lda + k0 + (s0 & 3) * 8, &As[s0 * 8]);
    GLD16(A  + (size_t)(m0 + (s1 >> 2)) * lda + k0 + (s1 & 3) * 8, &As[s1 * 8]);
    GLD16(Bw + (size_t)(n0 + (s0 >> 2)) * ldb + k0 + (s0 & 3) * 8, &Bs[s0 * 8]);
    GLD16(Bw + (size_t)(n0 + (s1 >> 2)) * ldb + k0 + (s1 & 3) * 8, &Bs[s1 * 8]);
    __syncthreads();
    const unsigned short *ap[4], *bp[4];
#pragma unroll
    for (int i = 0; i < 4; ++i) {
      ap[i] = &As[(wm + 16 * i + fr) * 32 + fo];
      bp[i] = &Bs[(wn + 16 * i + fr) * 32 + fo];
    }
#pragma unroll
    for (int i = 0; i < 4; ++i)
#pragma unroll
      for (int j = 0; j < 4; ++j)
        acc[i][j] = mfma16(ap[i], bp[j], acc[i][j]);
  }
  const int cr = (l >> 4) * 4, cc = l & 15;
  unsigned short* Cb = (unsigned short*)Cv;
#pragma unroll
  for (int j = 0; j < 4; ++j) {
    int n = n0 + wn + 16 * j + cc;
    float bv = bias[n];
#pragma unroll
    for (int i = 0; i < 4; ++i)
#pragma unroll
      for (int r = 0; r < 4; ++r) {
        int m = m0 + wm + 16 * i + cr + r;
        Cb[(size_t)m * ldc + n] = f2bf(acc[i][j][r] + bv);
      }
  }
}

// ---------------------------------------------------------------------------
// dec_gemm: decoder loss GEMM, 128x128 tile, BK=64 as two BK=32 halves
// (8 barrier-pairs instead of 16; 32 MFMA/wave/iter; acc stays 4x4=64 VGPR).
// K=512, single-buffer syncthreads loop, m97 addressing per half.
// 3136 blocks: n = (id&7)+8*(id>>6) (<391 guard), m = (id>>3)&7;
// same-n group => same XCD. Epilogue: softplus recon loss vs xmask bits.
// ---------------------------------------------------------------------------
__global__ __launch_bounds__(256) void dec_gemm(
    const unsigned short* __restrict__ A,      // Gb 1024x512
    const unsigned short* __restrict__ Bw,     // w2n 50000(+pad)x512
    const float* __restrict__ bias,
    const unsigned int* __restrict__ xmask, float* __restrict__ loss, int Nvalid)
{
  __shared__ __align__(16) unsigned short As[2][128 * 32];  // 16 KB (k-halves)
  __shared__ __align__(16) unsigned short Bs[2][128 * 32];  // 16 KB
  __shared__ unsigned int msk[128][4];                      // 2 KB
  __shared__ float red[4];
  const int tid = threadIdx.x;
  const int id = blockIdx.x;
  const int n = (id & 7) + 8 * (id >> 6);
  if (n >= 391) return;
  const int m0 = ((id >> 3) & 7) * 128;
  const int n0 = n * 128;
  const int w = tid >> 6, l = tid & 63;
  const int wm = (w >> 1) * 64, wn = (w & 1) * 64;
  const int fr = l & 15, fo = (l >> 4) * 8;
  const int s0 = tid, s1 = tid + 256;
  const unsigned short* Ar0 = A  + (size_t)(m0 + (s0 >> 2)) * 512 + (s0 & 3) * 8;
  const unsigned short* Ar1 = A  + (size_t)(m0 + (s1 >> 2)) * 512 + (s1 & 3) * 8;
  const unsigned short* Br0 = Bw + (size_t)(n0 + (s0 >> 2)) * 512 + (s0 & 3) * 8;
  const unsigned short* Br1 = Bw + (size_t)(n0 + (s1 >> 2)) * 512 + (s1 & 3) * 8;
  f32x4 acc[4][4] = {};
  for (int it = 0; it < 8; ++it) {
    int k0 = it * 64;
    __syncthreads();
    GLD16(Ar0 + k0,      &As[0][s0 * 8]);
    GLD16(Ar1 + k0,      &As[0][s1 * 8]);
    GLD16(Br0 + k0,      &Bs[0][s0 * 8]);
    GLD16(Br1 + k0,      &Bs[0][s1 * 8]);
    GLD16(Ar0 + k0 + 32, &As[1][s0 * 8]);
    GLD16(Ar1 + k0 + 32, &As[1][s1 * 8]);
    GLD16(Br0 + k0 + 32, &Bs[1][s0 * 8]);
    GLD16(Br1 + k0 + 32, &Bs[1][s1 * 8]);
    __syncthreads();
#pragma unroll
    for (int h = 0; h < 2; ++h) {
      const unsigned short *ap[4], *bp[4];
#pragma unroll
      for (int i = 0; i < 4; ++i) {
        ap[i] = &As[h][(wm + 16 * i + fr) * 32 + fo];
        bp[i] = &Bs[h][(wn + 16 * i + fr) * 32 + fo];
      }
#pragma unroll
      for (int i = 0; i < 4; ++i)
#pragma unroll
        for (int j = 0; j < 4; ++j)
          acc[i][j] = mfma16(ap[i], bp[j], acc[i][j]);
    }
  }
  // stage mask tile: 128 rows x 4 words
  {
    int row = tid >> 1, p = tid & 1;
    *(uint2*)&msk[row][p * 2] =
        *(const uint2*)(xmask + (size_t)(m0 + row) * MW + (n0 >> 5) + p * 2);
  }
  __syncthreads();
  const int cr = (l >> 4) * 4, cc = l & 15;
  float ts = 0.f;
#pragma unroll
  for (int j = 0; j < 4; ++j) {
    int nl = wn + 16 * j + cc;
    int nn = n0 + nl;
    if (nn < Nvalid) {
      float bv = bias[nn];
#pragma unroll
      for (int i = 0; i < 4; ++i)
#pragma unroll
        for (int r = 0; r < 4; ++r) {
          int ml = wm + 16 * i + cr + r;
          float lg = acc[i][j][r] + bv;
          float sp = fmaxf(lg, 0.f) + __logf(1.f + __expf(-fabsf(lg)));
          unsigned word = msk[ml][nl >> 5];
          ts += sp - (((word >> (nl & 31)) & 1u) ? lg : 0.f);
        }
    }
  }
  for (int off = 32; off > 0; off >>= 1) ts += __shfl_xor(ts, off);
  if (l == 0) red[w] = ts;
  __syncthreads();
  if (tid == 0) atomicAdd(loss, red[0] + red[1] + red[2] + red[3]);
}

// ---------------------------------------------------------------------------
// gemm64<EPI>: 64x64 tile GLD16 bf16 GEMM for the mid-chain (single-buffer)
// ---------------------------------------------------------------------------
template<int EPI>
__global__ __launch_bounds__(256) void gemm64(
    const unsigned short* __restrict__ A, int lda,
    const unsigned short* __restrict__ Bw, int ldb,
    const float* __restrict__ bias, void* __restrict__ Cv, int ldc, int K,
    const void* __restrict__ R0, const void* __restrict__ R1, const void* __restrict__ R2,
    void* __restrict__ W0, void* __restrict__ W1, float* __restrict__ loss)
{
  __shared__ __align__(16) unsigned short As[64 * 32];
  __shared__ __align__(16) unsigned short Bs[64 * 32];
  __shared__ float red[4];
  const int tid = threadIdx.x;
  const int m0 = blockIdx.x * 64, n0 = blockIdx.y * 64;
  const int w = tid >> 6, l = tid & 63;
  const int wm = (w >> 1) * 32, wn = (w & 1) * 32;
  const int fr = l & 15, fo = (l >> 4) * 8;
  const int srow = tid >> 2, scol = (tid & 3) * 8;
  f32x4 acc[2][2] = {};
  for (int k0 = 0; k0 < K; k0 += 32) {
    __syncthreads();
    GLD16(A  + (size_t)(m0 + srow) * lda + k0 + scol, &As[tid * 8]);
    GLD16(Bw + (size_t)(n0 + srow) * ldb + k0 + scol, &Bs[tid * 8]);
    __syncthreads();
    const unsigned short* ap0 = &As[(wm +      fr) * 32 + fo];
    const unsigned short* ap1 = &As[(wm + 16 + fr) * 32 + fo];
    const unsigned short* bp0 = &Bs[(wn +      fr) * 32 + fo];
    const unsigned short* bp1 = &Bs[(wn + 16 + fr) * 32 + fo];
    acc[0][0] = mfma16(ap0, bp0, acc[0][0]);
    acc[0][1] = mfma16(ap0, bp1, acc[0][1]);
    acc[1][0] = mfma16(ap1, bp0, acc[1][0]);
    acc[1][1] = mfma16(ap1, bp1, acc[1][1]);
  }
  const int cr = (l >> 4) * 4, cc = l & 15;
  float ts = 0.f;
#pragma unroll
  for (int i = 0; i < 2; ++i)
#pragma unroll
    for (int j = 0; j < 2; ++j) {
      int n = n0 + wn + 16 * j + cc;
      float bv = bias[n];
#pragma unroll
      for (int r = 0; r < 4; ++r) {
        int m = m0 + wm + 16 * i + cr + r;
        float v = acc[i][j][r] + bv;
        size_t idx = (size_t)m * ldc + n;
        if (EPI == 0) ((float*)Cv)[idx] = v;
        if (EPI == 1) ((unsigned short*)Cv)[idx] = f2bf(v);
        if (EPI == 2) ((unsigned short*)Cv)[idx] = f2bf(gelu_f(v));
        if (EPI == 3) {
          ((float*)Cv)[idx] = v;
          ((unsigned short*)W0)[idx] = f2bf(v);
          float zt = ((const float*)R1)[m] * v +
                     ((const float*)R2)[m] * ((const float*)R0)[idx];
          ((unsigned short*)W1)[idx] = f2bf(zt);
        }
        if (EPI == 4) {
          v += ((const float*)R0)[idx];
          ((unsigned short*)Cv)[idx] = f2bf(v);
        }
        if (EPI == 5) {
          v += bf2f(((const unsigned short*)R0)[idx]);
          float d = v - ((const float*)R1)[idx];
          ts += d * d;
        }
      }
    }
  if (EPI == 5) {
    for (int off = 32; off > 0; off >>= 1) ts += __shfl_xor(ts, off);
    if (l == 0) red[w] = ts;
    __syncthreads();
    if (tid == 0) atomicAdd(loss, red[0] + red[1] + red[2] + red[3]);
  }
}

// H1b = gelu(sum_k P0[k]+P1[k] + enc_b1) -> bf16, 1024x512; 32-slice reduce
__global__ __launch_bounds__(256) void h1_epi(const float* __restrict__ P0,
                                              const float* __restrict__ P1,
                                              const float* __restrict__ b,
                                              unsigned short* __restrict__ H) {
  int i = blockIdx.x * 256 + threadIdx.x;
  float s = b[i & 511];
#pragma unroll
  for (int k = 0; k < 16; ++k) s += P0[(size_t)k * 524288 + i];
#pragma unroll
  for (int k = 0; k < 16; ++k) s += P1[(size_t)k * 524288 + i];
  H[i] = f2bf(gelu_f(s));
}

// gather neighbors -> bf16 (one block per batch row, 20 neighbors)
__global__ __launch_bounds__(256) void gather_nb(
    const int* __restrict__ uid, const int* __restrict__ nidx,
    const float* __restrict__ emb, unsigned short* __restrict__ nb)
{
  int b = blockIdx.x, d = threadIdx.x;
  const int* np = nidx + uid[b] * 20;
#pragma unroll
  for (int j = 0; j < 20; ++j) {
    int idx = np[j];
    nb[((size_t)b * 20 + j) * 256 + d] = f2bf(emb[(size_t)idx * 256 + d]);
  }
}

// cross-attention core: 20 keys, one wave per (b, head); kvh bf16
__global__ __launch_bounds__(256) void attn_k(
    const float* __restrict__ qh, const unsigned short* __restrict__ kvh,
    unsigned short* __restrict__ o)
{
  int b = blockIdx.x, tid = threadIdx.x;
  int h = tid >> 6, d = tid & 63;
  float qv = qh[(size_t)b * 256 + h * 64 + d];
  const unsigned short* kbase = kvh + (size_t)b * 20 * 512 + h * 64 + d;
  const unsigned short* vbase = kbase + 256;
  float s[20];
#pragma unroll
  for (int k = 0; k < 20; ++k) {
    float p = qv * bf2f(kbase[k * 512]);
    for (int off = 32; off > 0; off >>= 1) p += __shfl_xor(p, off);
    s[k] = p * 0.125f;
  }
  float mx = s[0];
#pragma unroll
  for (int k = 1; k < 20; ++k) mx = fmaxf(mx, s[k]);
  float sum = 0.f;
#pragma unroll
  for (int k = 0; k < 20; ++k) { s[k] = __expf(s[k] - mx); sum += s[k]; }
  float inv = 1.f / sum;
  float ov = 0.f;
#pragma unroll
  for (int k = 0; k < 20; ++k) ov += s[k] * bf2f(vbase[k * 512]);
  o[(size_t)b * 256 + h * 64 + d] = f2bf(ov * inv);
}

// LayerNorm(X + Y), bf16 in/out
__global__ __launch_bounds__(256) void ln_k(
    const unsigned short* __restrict__ X, const unsigned short* __restrict__ Y,
    const float* __restrict__ g, const float* __restrict__ bb,
    unsigned short* __restrict__ out)
{
  __shared__ float rs[4], rs2[4];
  int b = blockIdx.x, d = threadIdx.x;
  size_t i = (size_t)b * 256 + d;
  float v = bf2f(X[i]) + bf2f(Y[i]);
  float s = v, s2 = v * v;
  for (int off = 32; off > 0; off >>= 1) { s += __shfl_xor(s, off); s2 += __shfl_xor(s2, off); }
  int w = d >> 6, l = d & 63;
  if (l == 0) { rs[w] = s; rs2[w] = s2; }
  __syncthreads();
  s  = rs[0] + rs[1] + rs[2] + rs[3];
  s2 = rs2[0] + rs2[1] + rs2[2] + rs2[3];
  float mean = s * (1.f / 256.f);
  float var  = s2 * (1.f / 256.f) - mean * mean;
  out[i] = f2bf((v - mean) * rsqrtf(var + 1e-5f) * g[d] + bb[d]);
}

__global__ void final_k(const float* __restrict__ scal, float* __restrict__ out) {
  out[0] = scal[0] * (1.f / (1024.f * 256.f)) + 0.1f * scal[1] * (1.f / (1024.f * 50000.f));
}

// ---------------------------------------------------------------------------
extern "C" void kernel_launch(void* const* d_in, const int* in_sizes, int n_in,
                              void* d_out, int out_size, void* d_ws, size_t ws_size,
                              hipStream_t stream) {
  const float* x0      = (const float*)d_in[0];
  const int*   uid     = (const int*)  d_in[1];
  const int*   t       = (const int*)  d_in[2];
  const float* noise   = (const float*)d_in[3];
  const int*   nidx    = (const int*)  d_in[4];
  const float* item_emb= (const float*)d_in[5];
  const float* enc_w1  = (const float*)d_in[6];
  const float* enc_b1  = (const float*)d_in[7];
  const float* enc_w2  = (const float*)d_in[8];
  const float* enc_b2  = (const float*)d_in[9];
  const float* dec_w1  = (const float*)d_in[10];
  const float* dec_b1  = (const float*)d_in[11];
  const float* dec_w2  = (const float*)d_in[12];
  const float* dec_b2  = (const float*)d_in[13];
  const float* up_w    = (const float*)d_in[14];
  const float* up_b    = (const float*)d_in[15];
  const float* ip_w    = (const float*)d_in[16];
  const float* ip_b    = (const float*)d_in[17];
  const float* te_w1   = (const float*)d_in[18];
  const float* te_b1   = (const float*)d_in[19];
  const float* te_w2   = (const float*)d_in[20];
  const float* te_b2   = (const float*)d_in[21];
  const float* ca_wqkv = (const float*)d_in[22];
  const float* ca_bqkv = (const float*)d_in[23];
  const float* ca_wo   = (const float*)d_in[24];
  const float* ca_bo   = (const float*)d_in[25];
  const float* sa_wqkv = (const float*)d_in[26];
  const float* sa_bqkv = (const float*)d_in[27];
  const float* sa_wo   = (const float*)d_in[28];
  const float* sa_bo   = (const float*)d_in[29];
  const float* n1_g    = (const float*)d_in[30];
  const float* n1_b    = (const float*)d_in[31];
  const float* n2_g    = (const float*)d_in[32];
  const float* n2_b    = (const float*)d_in[33];
  const float* ff_w1   = (const float*)d_in[34];
  const float* ff_b1   = (const float*)d_in[35];
  const float* ff_w2   = (const float*)d_in[36];
  const float* ff_b2   = (const float*)d_in[37];
  (void)in_sizes; (void)n_in; (void)out_size; (void)ws_size;

  float* ws   = (float*)d_ws;
  float* scal = ws;                    // 4 (diff, recon)
  float* sab  = ws + 4;                // 1024
  float* s1ab = sab + 1024;
  float* te   = s1ab + 1024;           // 1024*256
  float* qhf  = te + 262144;           // 1024*256
  float* z0f  = qhf + 262144;          // 1024*256
  float* bkv  = z0f + 262144;          // 512
  float* bsa  = bkv + 512;             // 256
  unsigned int* xmask = (unsigned int*)(bsa + 256);           // 1024*MW
  // P-pool bank0: slices 0-15 (33,554,432 B) aliases [nbb|kvhb|f1b|Gb]
  unsigned short* sh  = (unsigned short*)(xmask + 1024 * MW);
  float*          OUTp = (float*)sh;                          // 8,388,608 f32
  unsigned short* nbb  = sh;                                  // 20480*256
  unsigned short* kvhb = nbb + 5242880;                       // 20480*512
  unsigned short* f1b  = kvhb + 10485760;                     // 1024*512
  unsigned short* Gb   = f1b + 524288;                        // 1024*512
  unsigned short* x0b  = Gb + 524288;                         // dead region: holds w2n + xmaskT
  unsigned short* w2n  = x0b;                                 // 25.6M shorts
  unsigned int*   xmaskT = (unsigned int*)(x0b + 26214400);   // MW*1024 words (6.4 MB)
  unsigned short* w1b  = x0b + (size_t)1024 * KP;             // 512*KP
  unsigned short* H1b  = w1b + (size_t)512 * KP;              // 1024*512
  unsigned short* z0b  = H1b + 524288;
  unsigned short* ztb  = z0b + 262144;
  unsigned short* qpb  = ztb + 262144;
  unsigned short* ob   = qpb + 262144;
  unsigned short* cab  = ob  + 262144;
  unsigned short* hb   = cab + 262144;
  unsigned short* saob = hb  + 262144;
  unsigned short* h2b  = saob+ 262144;
  unsigned short* enc_w2b = h2b + 262144;                     // 131072
  unsigned short* up_wb   = enc_w2b + 131072;
  unsigned short* ca_wqb  = up_wb + 65536;
  unsigned short* ca_wob  = ca_wqb + 65536;
  unsigned short* ff_w1b  = ca_wob + 65536;
  unsigned short* ff_w2b  = ff_w1b + 131072;
  unsigned short* dec_w1b = ff_w2b + 131072;
  unsigned short* Wkv     = dec_w1b + 131072;
  unsigned short* Wsab    = Wkv + 131072;
  // P-pool bank1: slices 16-31
  float*          OUTp2   = (float*)(Wsab + 131072);          // 8,388,608 f32

  hipMemsetAsync(scal, 0, 4 * sizeof(float), stream);

  // critical prep: bits (both layouts) + w1 bf16 — thin blocks, barrier-light
  prep_crit<<<PC_W1, 256, 0, stream>>>(x0, xmask, xmaskT, enc_w1, w1b);

  // enc GEMM (BK=64, transposed-mask GLD4) + all independent late prep fused
  enc_fused<<<EF_TE, 256, 0, stream>>>(
      xmaskT, w1b, OUTp, OUTp2,
      dec_w2, w2n,
      enc_w2, up_w, ca_wqkv, ca_wo, ff_w1, ff_w2, dec_w1,
      enc_w2b, up_wb, ca_wqb, ca_wob, ff_w1b, ff_w2b, dec_w1b,
      ca_wqkv, ca_bqkv, ip_w, ip_b, sa_wqkv, sa_bqkv, sa_wo, sa_bo,
      Wkv, bkv, Wsab, bsa,
      t, te_w1, te_b1, te_w2, te_b2, te, sab, s1ab);
  h1_epi<<<2048, 256, 0, stream>>>(OUTp, OUTp2, enc_b1, H1b);  // OUTp dead after

  // kv path (P-pool bank0 live again: OUTp dead)
  gather_nb<<<1024, 256, 0, stream>>>(uid, nidx, item_emb, nbb);
  gemm128<<<dim3(160, 4), 256, 0, stream>>>(
      nbb, 256, Wkv, 256, bkv, kvhb, 512, 256);

  // z0 GEMM + fused z_t
  gemm64<3><<<dim3(16, 4), 256, 0, stream>>>(
      H1b, 512, enc_w2b, 512, enc_b2, z0f, 256, 512, noise, sab, s1ab, z0b, ztb, nullptr);

  // q path
  gemm64<4><<<dim3(16, 4), 256, 0, stream>>>(
      ztb, 256, up_wb, 256, up_b, qpb, 256, 256, te, nullptr, nullptr, nullptr, nullptr, nullptr);
  gemm64<0><<<dim3(16, 4), 256, 0, stream>>>(
      qpb, 256, ca_wqb, 256, ca_bqkv, qhf, 256, 256,
      nullptr, nullptr, nullptr, nullptr, nullptr, nullptr);

  // attention + out-proj + LN1
  attn_k<<<1024, 256, 0, stream>>>(qhf, kvhb, ob);
  gemm64<1><<<dim3(16, 4), 256, 0, stream>>>(
      ob, 256, ca_wob, 256, ca_bo, cab, 256, 256,
      nullptr, nullptr, nullptr, nullptr, nullptr, nullptr);
  ln_k<<<1024, 256, 0, stream>>>(qpb, cab, n1_g, n1_b, hb);

  // self-attn (seq=1, composed) + LN2
  gemm64<1><<<dim3(16, 4), 256, 0, stream>>>(
      hb, 256, Wsab, 256, bsa, saob, 256, 256,
      nullptr, nullptr, nullptr, nullptr, nullptr, nullptr);
  ln_k<<<1024, 256, 0, stream>>>(hb, saob, n2_g, n2_b, h2b);

  // FF with fused residual + diffusion loss
  gemm64<2><<<dim3(16, 8), 256, 0, stream>>>(
      h2b, 256, ff_w1b, 256, ff_b1, f1b, 512, 256,
      nullptr, nullptr, nullptr, nullptr, nullptr, nullptr);
  gemm64<5><<<dim3(16, 4), 256, 0, stream>>>(
      f1b, 512, ff_w2b, 512, ff_b2, nullptr, 256, 512,
      h2b, z0f, nullptr, nullptr, nullptr, &scal[0]);

  // decoder: G = gelu(z0@dec_w1^T+b) bf16, then BK=64 GEMM + fused loss
  gemm64<2><<<dim3(16, 8), 256, 0, stream>>>(
      z0b, 256, dec_w1b, 256, dec_b1, Gb, 512, 256,
      nullptr, nullptr, nullptr, nullptr, nullptr, nullptr);
  dec_gemm<<<3136, 256, 0, stream>>>(
      Gb, w2n, dec_b2, xmask, &scal[1], NI);

  final_k<<<1, 1, 0, stream>>>(scal, (float*)d_out);
}